// Round 1
// baseline (694.332 us; speedup 1.0000x reference)
//
#include <hip/hip_runtime.h>

#define HN 8
#define NN 4096
#define CC 384
#define DD 48
#define DP 64   // padded feature dim (49 -> 64)
#define DI 49   // extended i-range (k appended with constant-1 channel)

__device__ __forceinline__ float4 ld4(const float* p){ return *reinterpret_cast<const float4*>(p); }
__device__ __forceinline__ void st4(float* p, const float4& v){ *reinterpret_cast<float4*>(p) = v; }

// C[m][n] = sum_k A[m][k]*B[n][k] + bias[n]   (both row-major, K contiguous)
__global__ __launch_bounds__(256) void gemm_nt(const float* __restrict__ A,
                                               const float* __restrict__ B,
                                               const float* __restrict__ bias,
                                               float* __restrict__ Cm,
                                               int M, int Nc, int K) {
  __shared__ float As[16*68];
  __shared__ float Bs[16*68];
  const int tid = threadIdx.x;
  const int m0 = blockIdx.x * 64;
  const int n0 = blockIdx.y * 64;
  const int lr = tid >> 2;            // 0..63 staging row
  const int lc = (tid & 3) << 2;      // 0,4,8,12 staging col
  const int r0 = (tid & 15) << 2;     // output 4-row group
  const int c0 = (tid >> 4) << 2;     // output 4-col group
  float acc[4][4] = {{0.f}};
  for (int k0 = 0; k0 < K; k0 += 16) {
    float4 a = ld4(A + (size_t)(m0 + lr) * K + k0 + lc);
    float4 b = ld4(B + (size_t)(n0 + lr) * K + k0 + lc);
    __syncthreads();
    As[(lc+0)*68+lr]=a.x; As[(lc+1)*68+lr]=a.y; As[(lc+2)*68+lr]=a.z; As[(lc+3)*68+lr]=a.w;
    Bs[(lc+0)*68+lr]=b.x; Bs[(lc+1)*68+lr]=b.y; Bs[(lc+2)*68+lr]=b.z; Bs[(lc+3)*68+lr]=b.w;
    __syncthreads();
#pragma unroll
    for (int kk = 0; kk < 16; ++kk) {
      float4 av = ld4(&As[kk*68 + r0]);
      float4 bv = ld4(&Bs[kk*68 + c0]);
      float aa[4] = {av.x, av.y, av.z, av.w};
      float bb[4] = {bv.x, bv.y, bv.z, bv.w};
#pragma unroll
      for (int u = 0; u < 4; ++u)
#pragma unroll
        for (int w = 0; w < 4; ++w)
          acc[u][w] += aa[u] * bb[w];
    }
  }
#pragma unroll
  for (int u = 0; u < 4; ++u) {
    float4 o;
    o.x = acc[u][0] + bias[n0+c0+0];
    o.y = acc[u][1] + bias[n0+c0+1];
    o.z = acc[u][2] + bias[n0+c0+2];
    o.w = acc[u][3] + bias[n0+c0+3];
    st4(Cm + (size_t)(m0 + r0 + u) * Nc + n0 + c0, o);
  }
}

// One wave per (h, n): normalize q/k, build extended padded Q~/K~/V1 buffers [H][N][64].
__global__ __launch_bounds__(256) void prep_kernel(const float* __restrict__ qkv,
                                                   const float* __restrict__ temperature,
                                                   float* __restrict__ Qb,
                                                   float* __restrict__ Kb,
                                                   float* __restrict__ Vb) {
  const int lane = threadIdx.x & 63;
  const int wv = threadIdx.x >> 6;
  const int gw = blockIdx.x * 4 + wv;   // 0..32767
  const int h = gw & 7;
  const int n = gw >> 3;
  const float* row = qkv + (size_t)n * (3*CC) + h * DD;
  float qv = (lane < DD) ? row[lane] : 0.f;
  float kv = (lane < DD) ? row[CC + lane] : 0.f;
  float vv = (lane >= 1 && lane <= DD) ? row[2*CC + lane - 1] : 0.f;
  const float CINV = 0.05103103630798288f;     // 384^-0.5
  float qs = qv * CINV;
  float q2 = qs * qs;
  float k2 = kv * kv;
#pragma unroll
  for (int off = 32; off > 0; off >>= 1) {
    q2 += __shfl_xor(q2, off);
    k2 += __shfl_xor(k2, off);
  }
  const float S4 = 2.6321480259049848f;        // 48^0.25
  float temp = temperature[h];
  float qn = qs / fmaxf(sqrtf(q2), 1e-12f) * (S4 * temp);
  float kn = kv / fmaxf(sqrtf(k2), 1e-12f) * S4;
  // q~[48] = sqrt(48) (so A*2c = s^2*B), k~[48] = 1
  float qo = (lane < DD) ? qn : ((lane == DD) ? 6.928203230275509f : 0.f);
  float ko = (lane < DD) ? kn : ((lane == DD) ? 1.f : 0.f);
  float vo = (lane == 0) ? (1.f/NN) : ((lane <= DD) ? vv * (1.f/NN) : 0.f);
  size_t base = ((size_t)h * NN + n) * DP + lane;
  Qb[base] = qo;
  Kb[base] = ko;
  Vb[base] = vo;
}

// M[part][h][i][j][f] = sum_{n in part} k~[n][i] * k~[n][j] * v1[n][f]
__global__ __launch_bounds__(256) void kvmod_kernel(const float* __restrict__ Kb,
                                                    const float* __restrict__ Vb,
                                                    float* __restrict__ M) {
  __shared__ float Ks[64*64];
  __shared__ float Vs[64*64];
  const int tid = threadIdx.x;
  const int i = blockIdx.x;        // 0..48
  const int h = blockIdx.y;
  const int part = blockIdx.z;     // 0..1 (n-split for occupancy)
  const int j0 = (tid & 15) << 2;
  const int f0 = (tid >> 4) << 2;
  float acc[4][4] = {{0.f}};
  const float* kb = Kb + ((size_t)h * NN + part * 2048) * DP;
  const float* vb = Vb + ((size_t)h * NN + part * 2048) * DP;
  for (int t = 0; t < 32; ++t) {
    __syncthreads();
#pragma unroll
    for (int p = 0; p < 4; ++p) {
      int v = (tid + p*256) * 4;
      st4(&Ks[v], ld4(kb + (size_t)t*4096 + v));
      st4(&Vs[v], ld4(vb + (size_t)t*4096 + v));
    }
    __syncthreads();
#pragma unroll 8
    for (int nn = 0; nn < 64; ++nn) {
      float ki = Ks[nn*64 + i];                 // uniform address -> LDS broadcast
      float4 kj = ld4(&Ks[nn*64 + j0]);
      float4 vf = ld4(&Vs[nn*64 + f0]);
      float w[4]  = {ki*kj.x, ki*kj.y, ki*kj.z, ki*kj.w};
      float vf4[4] = {vf.x, vf.y, vf.z, vf.w};
#pragma unroll
      for (int u = 0; u < 4; ++u)
#pragma unroll
        for (int q = 0; q < 4; ++q)
          acc[u][q] += w[u] * vf4[q];
    }
  }
  float* out = M + (((size_t)part * HN + h) * DI + i) * 4096;
#pragma unroll
  for (int u = 0; u < 4; ++u)
    st4(out + (j0+u)*64 + f0, make_float4(acc[u][0], acc[u][1], acc[u][2], acc[u][3]));
}

// y[n][f] = 0.5 * sum_{i,j} q~[n][i] q~[n][j] M[i][j][f] + 24 * M[48][48][f];
// out_head[n][f-1] = y[n][f] / y[n][0]
__global__ __launch_bounds__(256) void y_kernel(const float* __restrict__ Qb,
                                                const float* __restrict__ M,
                                                float* __restrict__ attn) {
  __shared__ float Qs[128*65];   // stride 65: conflict-free scalar column reads
  __shared__ float Ms[64*64];
  __shared__ float ynorm[128];
  const int tid = threadIdx.x;
  const int h = blockIdx.y;
  const int n0 = blockIdx.x * 128;
  const float* qb = Qb + ((size_t)h * NN + n0) * DP;
#pragma unroll
  for (int p = 0; p < 8; ++p) {
    int v = tid + p*256;       // 0..2047 float4 index
    int r = v >> 4;            // 0..127
    int c = (v & 15) << 2;
    float4 q = ld4(qb + (size_t)r*DP + c);
    float* dst = &Qs[r*65 + c];
    dst[0]=q.x; dst[1]=q.y; dst[2]=q.z; dst[3]=q.w;
  }
  const int fg = tid & 15;
  const int rg = tid >> 4;
  const int f0 = fg << 2;
  const int r0 = rg << 3;
  float acc[8][4] = {{0.f}};
  const float* M0 = M + ((size_t)h * DI) * 4096;
  const float* M1 = M + ((size_t)(HN + h) * DI) * 4096;
  for (int i = 0; i < DI; ++i) {
    __syncthreads();
#pragma unroll
    for (int p = 0; p < 4; ++p) {
      int v = (tid + p*256) * 4;
      float4 a = ld4(M0 + (size_t)i*4096 + v);
      float4 b = ld4(M1 + (size_t)i*4096 + v);
      st4(&Ms[v], make_float4(a.x+b.x, a.y+b.y, a.z+b.z, a.w+b.w));
    }
    __syncthreads();
    float qi[8];
#pragma unroll
    for (int rr = 0; rr < 8; ++rr) qi[rr] = Qs[(r0+rr)*65 + i];
    float w[8][4] = {{0.f}};
#pragma unroll 4
    for (int j = 0; j < 64; ++j) {
      float4 m = ld4(&Ms[j*64 + f0]);
#pragma unroll
      for (int rr = 0; rr < 8; ++rr) {
        float qj = Qs[(r0+rr)*65 + j];
        w[rr][0] += qj*m.x; w[rr][1] += qj*m.y; w[rr][2] += qj*m.z; w[rr][3] += qj*m.w;
      }
    }
#pragma unroll
    for (int rr = 0; rr < 8; ++rr) {
      acc[rr][0] += qi[rr]*w[rr][0];
      acc[rr][1] += qi[rr]*w[rr][1];
      acc[rr][2] += qi[rr]*w[rr][2];
      acc[rr][3] += qi[rr]*w[rr][3];
    }
  }
  // Ms still holds slice i=48; M_ext[48][48][f] = sum(v1)[f]
  float4 ml = ld4(&Ms[48*64 + f0]);
  float y[8][4];
#pragma unroll
  for (int rr = 0; rr < 8; ++rr) {
    y[rr][0] = 0.5f*acc[rr][0] + 24.f*ml.x;
    y[rr][1] = 0.5f*acc[rr][1] + 24.f*ml.y;
    y[rr][2] = 0.5f*acc[rr][2] + 24.f*ml.z;
    y[rr][3] = 0.5f*acc[rr][3] + 24.f*ml.w;
  }
  if (fg == 0) {
#pragma unroll
    for (int rr = 0; rr < 8; ++rr) ynorm[r0+rr] = y[rr][0];
  }
  __syncthreads();
#pragma unroll
  for (int rr = 0; rr < 8; ++rr) {
    float inv = 1.f / ynorm[r0+rr];
#pragma unroll
    for (int ff = 0; ff < 4; ++ff) {
      int f = f0 + ff;
      if (f >= 1 && f <= DD)
        attn[(size_t)(n0+r0+rr)*CC + h*DD + (f-1)] = y[rr][ff] * inv;
    }
  }
}

extern "C" void kernel_launch(void* const* d_in, const int* in_sizes, int n_in,
                              void* d_out, int out_size, void* d_ws, size_t ws_size,
                              hipStream_t stream) {
  const float* x      = (const float*)d_in[0];
  const float* qkv_w  = (const float*)d_in[1];
  const float* qkv_b  = (const float*)d_in[2];
  const float* proj_w = (const float*)d_in[3];
  const float* proj_b = (const float*)d_in[4];
  const float* temp   = (const float*)d_in[5];
  float* ws = (float*)d_ws;

  float* qkv = ws;                        // 4096*1152 = 4718592 floats (attn aliases this later)
  float* Qb  = ws + 4718592;              // 8*4096*64 = 2097152
  float* Kb  = Qb + 2097152;              // 2097152
  float* Vb  = Kb + 2097152;              // 2097152
  float* Mb  = Vb + 2097152;              // 2*8*49*4096 = 3211264
  float* attn = qkv;                      // qkv is dead after prep_kernel

  {
    dim3 g(4096/64, 1152/64);
    gemm_nt<<<g, 256, 0, stream>>>(x, qkv_w, qkv_b, qkv, 4096, 1152, 384);
  }
  prep_kernel<<<8192, 256, 0, stream>>>(qkv, temp, Qb, Kb, Vb);
  {
    dim3 g(DI, HN, 2);
    kvmod_kernel<<<g, 256, 0, stream>>>(Kb, Vb, Mb);
  }
  {
    dim3 g(4096/128, HN);
    y_kernel<<<g, 256, 0, stream>>>(Qb, Mb, attn);
  }
  {
    dim3 g(4096/64, 384/64);
    gemm_nt<<<g, 256, 0, stream>>>(attn, proj_w, proj_b, (float*)d_out, 4096, 384, 384);
  }
}

// Round 2
// 452.958 us; speedup vs baseline: 1.5329x; 1.5329x over previous
//
#include <hip/hip_runtime.h>

#define HN 8
#define NN 4096
#define CC 384
#define DD 48
#define DP 64   // padded feature dim (49 -> 64)
#define DIS 50  // stored M slices: i = 0..48 real, 49 = zero pad

__device__ __forceinline__ float4 ld4(const float* p){ return *reinterpret_cast<const float4*>(p); }
__device__ __forceinline__ void st4(float* p, const float4& v){ *reinterpret_cast<float4*>(p) = v; }

// C[m][n] = sum_k A[m][k]*B[n][k] + bias[n]   (both row-major, K contiguous)
__global__ __launch_bounds__(256) void gemm_nt(const float* __restrict__ A,
                                               const float* __restrict__ B,
                                               const float* __restrict__ bias,
                                               float* __restrict__ Cm,
                                               int M, int Nc, int K) {
  __shared__ float As[16*68];
  __shared__ float Bs[16*68];
  const int tid = threadIdx.x;
  const int m0 = blockIdx.x * 64;
  const int n0 = blockIdx.y * 64;
  const int lr = tid >> 2;            // 0..63 staging row
  const int lc = (tid & 3) << 2;      // 0,4,8,12 staging col
  const int r0 = (tid & 15) << 2;     // output 4-row group
  const int c0 = (tid >> 4) << 2;     // output 4-col group
  float acc[4][4] = {{0.f}};
  for (int k0 = 0; k0 < K; k0 += 16) {
    float4 a = ld4(A + (size_t)(m0 + lr) * K + k0 + lc);
    float4 b = ld4(B + (size_t)(n0 + lr) * K + k0 + lc);
    __syncthreads();
    As[(lc+0)*68+lr]=a.x; As[(lc+1)*68+lr]=a.y; As[(lc+2)*68+lr]=a.z; As[(lc+3)*68+lr]=a.w;
    Bs[(lc+0)*68+lr]=b.x; Bs[(lc+1)*68+lr]=b.y; Bs[(lc+2)*68+lr]=b.z; Bs[(lc+3)*68+lr]=b.w;
    __syncthreads();
#pragma unroll
    for (int kk = 0; kk < 16; ++kk) {
      float4 av = ld4(&As[kk*68 + r0]);
      float4 bv = ld4(&Bs[kk*68 + c0]);
      float aa[4] = {av.x, av.y, av.z, av.w};
      float bb[4] = {bv.x, bv.y, bv.z, bv.w};
#pragma unroll
      for (int u = 0; u < 4; ++u)
#pragma unroll
        for (int w = 0; w < 4; ++w)
          acc[u][w] += aa[u] * bb[w];
    }
  }
#pragma unroll
  for (int u = 0; u < 4; ++u) {
    float4 o;
    o.x = acc[u][0] + bias[n0+c0+0];
    o.y = acc[u][1] + bias[n0+c0+1];
    o.z = acc[u][2] + bias[n0+c0+2];
    o.w = acc[u][3] + bias[n0+c0+3];
    st4(Cm + (size_t)(m0 + r0 + u) * Nc + n0 + c0, o);
  }
}

// One wave per (h, n): normalize q/k, build extended padded Q~/K~/V1 buffers [H][N][64].
__global__ __launch_bounds__(256) void prep_kernel(const float* __restrict__ qkv,
                                                   const float* __restrict__ temperature,
                                                   float* __restrict__ Qb,
                                                   float* __restrict__ Kb,
                                                   float* __restrict__ Vb) {
  const int lane = threadIdx.x & 63;
  const int wv = threadIdx.x >> 6;
  const int gw = blockIdx.x * 4 + wv;   // 0..32767
  const int h = gw & 7;
  const int n = gw >> 3;
  const float* row = qkv + (size_t)n * (3*CC) + h * DD;
  float qv = (lane < DD) ? row[lane] : 0.f;
  float kv = (lane < DD) ? row[CC + lane] : 0.f;
  float vv = (lane >= 1 && lane <= DD) ? row[2*CC + lane - 1] : 0.f;
  const float CINV = 0.05103103630798288f;     // 384^-0.5
  float qs = qv * CINV;
  float q2 = qs * qs;
  float k2 = kv * kv;
#pragma unroll
  for (int off = 32; off > 0; off >>= 1) {
    q2 += __shfl_xor(q2, off);
    k2 += __shfl_xor(k2, off);
  }
  const float S4 = 2.6321480259049848f;        // 48^0.25
  float temp = temperature[h];
  float qn = qs / fmaxf(sqrtf(q2), 1e-12f) * (S4 * temp);
  float kn = kv / fmaxf(sqrtf(k2), 1e-12f) * S4;
  // q~[48] = sqrt(48) (so A*2c = s^2*B), k~[48] = 1
  float qo = (lane < DD) ? qn : ((lane == DD) ? 6.928203230275509f : 0.f);
  float ko = (lane < DD) ? kn : ((lane == DD) ? 1.f : 0.f);
  float vo = (lane == 0) ? (1.f/NN) : ((lane <= DD) ? vv * (1.f/NN) : 0.f);
  size_t base = ((size_t)h * NN + n) * DP + lane;
  Qb[base] = qo;
  Kb[base] = ko;
  Vb[base] = vo;
}

// M[part][h][i][j][f] = sum_{n in part} k~[n][i] * k~[n][j] * v1[n][f]
// i runs 0..49; slice 49 is naturally zero (k~ padded with 0 there).
__global__ __launch_bounds__(256) void kvmod_kernel(const float* __restrict__ Kb,
                                                    const float* __restrict__ Vb,
                                                    float* __restrict__ M) {
  __shared__ float Ks[64*64];
  __shared__ float Vs[64*64];
  const int tid = threadIdx.x;
  const int i = blockIdx.x;        // 0..49
  const int h = blockIdx.y;
  const int part = blockIdx.z;     // 0..1 (n-split for occupancy)
  const int j0 = (tid & 15) << 2;
  const int f0 = (tid >> 4) << 2;
  float acc[4][4] = {{0.f}};
  const float* kb = Kb + ((size_t)h * NN + part * 2048) * DP;
  const float* vb = Vb + ((size_t)h * NN + part * 2048) * DP;
  for (int t = 0; t < 32; ++t) {
    __syncthreads();
#pragma unroll
    for (int p = 0; p < 4; ++p) {
      int v = (tid + p*256) * 4;
      st4(&Ks[v], ld4(kb + (size_t)t*4096 + v));
      st4(&Vs[v], ld4(vb + (size_t)t*4096 + v));
    }
    __syncthreads();
#pragma unroll 8
    for (int nn = 0; nn < 64; ++nn) {
      float ki = Ks[nn*64 + i];                 // uniform address -> LDS broadcast
      float4 kj = ld4(&Ks[nn*64 + j0]);
      float4 vf = ld4(&Vs[nn*64 + f0]);
      float w[4]  = {ki*kj.x, ki*kj.y, ki*kj.z, ki*kj.w};
      float vf4[4] = {vf.x, vf.y, vf.z, vf.w};
#pragma unroll
      for (int u = 0; u < 4; ++u)
#pragma unroll
        for (int q = 0; q < 4; ++q)
          acc[u][q] += w[u] * vf4[q];
    }
  }
  float* out = M + (((size_t)part * HN + h) * DIS + i) * 4096;
#pragma unroll
  for (int u = 0; u < 4; ++u)
    st4(out + (j0+u)*64 + f0, make_float4(acc[u][0], acc[u][1], acc[u][2], acc[u][3]));
}

// y[n][f] = 0.5 * sum_{i,j} q~i q~j M[i][j][f] + 24 * M[48][48][f]
// Triangle form (M symmetric): sum_i qi^2 M[i][i] + sum_{i<j} 2 qi qj M[i][j].
// out_head[n][f-1] = y[n][f] / y[n][0]
__global__ __launch_bounds__(256) void y_kernel(const float* __restrict__ Qb,
                                                const float* __restrict__ M,
                                                float* __restrict__ attn) {
  __shared__ float QsT[52*128];     // q transposed: QsT[i][row]
  __shared__ float Ms[2*64*64];     // 2 staged M slices (parts summed)
  __shared__ float ynorm[128];
  const int tid = threadIdx.x;
  const int h = blockIdx.y;
  const int n0 = blockIdx.x * 128;
  const float* qb = Qb + ((size_t)h * NN + n0) * DP;
  // stage Q transposed for i = 0..51 (i>=49 are zeros from prep padding)
  for (int v = tid; v < 13*128; v += 256) {
    int r = v & 127;
    int cg = v >> 7;              // 0..12
    float4 q = ld4(qb + (size_t)r*DP + cg*4);
    QsT[(cg*4+0)*128 + r] = q.x;
    QsT[(cg*4+1)*128 + r] = q.y;
    QsT[(cg*4+2)*128 + r] = q.z;
    QsT[(cg*4+3)*128 + r] = q.w;
  }
  const int fg = tid & 15;
  const int rg = tid >> 4;
  const int f0 = fg << 2;
  const int r0 = rg << 3;
  float acc[8][4] = {{0.f}};
  const float* M0 = M + ((size_t)h * DIS) * 4096;
  const float* M1 = M + ((size_t)(HN + h) * DIS) * 4096;
  for (int b = 0; b < 25; ++b) {
    const int i0 = 2*b;
    __syncthreads();
    // stage slices i0, i0+1 (8192 contiguous floats), parts summed
#pragma unroll
    for (int p = 0; p < 8; ++p) {
      int v = (tid + p*256) * 4;
      float4 a = ld4(M0 + (size_t)i0*4096 + v);
      float4 c = ld4(M1 + (size_t)i0*4096 + v);
      st4(&Ms[v], make_float4(a.x+c.x, a.y+c.y, a.z+c.z, a.w+c.w));
    }
    __syncthreads();
    float qi1[8][2], qi2[8][2];
#pragma unroll
    for (int rr = 0; rr < 8; ++rr) {
      qi1[rr][0] = QsT[(i0+0)*128 + r0 + rr];
      qi1[rr][1] = QsT[(i0+1)*128 + r0 + rr];
      qi2[rr][0] = qi1[rr][0] + qi1[rr][0];
      qi2[rr][1] = qi1[rr][1] + qi1[rr][1];
    }
    // diagonal-region j = i0: pair (i0,i0) coeff 1
    {
      float4 m0 = ld4(&Ms[0*4096 + i0*64 + f0]);
#pragma unroll
      for (int rr = 0; rr < 8; ++rr) {
        float c = qi1[rr][0] * qi1[rr][0];
        acc[rr][0] += c*m0.x; acc[rr][1] += c*m0.y;
        acc[rr][2] += c*m0.z; acc[rr][3] += c*m0.w;
      }
    }
    // diagonal-region j = i0+1: (i0,i0+1) coeff 2 ; (i0+1,i0+1) coeff 1
    {
      float4 m0 = ld4(&Ms[0*4096 + (i0+1)*64 + f0]);
      float4 m1 = ld4(&Ms[1*4096 + (i0+1)*64 + f0]);
#pragma unroll
      for (int rr = 0; rr < 8; ++rr) {
        float qj = qi1[rr][1];
        float c0 = qi2[rr][0] * qj;
        float c1 = qi1[rr][1] * qj;
        acc[rr][0] += c0*m0.x + c1*m1.x;
        acc[rr][1] += c0*m0.y + c1*m1.y;
        acc[rr][2] += c0*m0.z + c1*m1.z;
        acc[rr][3] += c0*m0.w + c1*m1.w;
      }
    }
    // uniform region j = i0+2 .. 49 (qj[49]=0, M[49]=0 -> harmless), coeff 2 both
#pragma unroll 2
    for (int j = i0+2; j < 50; ++j) {
      float4 qa = ld4(&QsT[j*128 + r0]);
      float4 qb2 = ld4(&QsT[j*128 + r0 + 4]);
      float qj[8] = {qa.x, qa.y, qa.z, qa.w, qb2.x, qb2.y, qb2.z, qb2.w};
      float4 m0 = ld4(&Ms[0*4096 + j*64 + f0]);
      float4 m1 = ld4(&Ms[1*4096 + j*64 + f0]);
#pragma unroll
      for (int rr = 0; rr < 8; ++rr) {
        float c0 = qi2[rr][0] * qj[rr];
        float c1 = qi2[rr][1] * qj[rr];
        acc[rr][0] += c0*m0.x + c1*m1.x;
        acc[rr][1] += c0*m0.y + c1*m1.y;
        acc[rr][2] += c0*m0.z + c1*m1.z;
        acc[rr][3] += c0*m0.w + c1*m1.w;
      }
    }
  }
  // epilogue: + 24 * Msum[48][48][f]
  float4 e0 = ld4(M0 + (size_t)48*4096 + 48*64 + f0);
  float4 e1 = ld4(M1 + (size_t)48*4096 + 48*64 + f0);
  float ml[4] = {e0.x+e1.x, e0.y+e1.y, e0.z+e1.z, e0.w+e1.w};
  float y[8][4];
#pragma unroll
  for (int rr = 0; rr < 8; ++rr)
#pragma unroll
    for (int k = 0; k < 4; ++k)
      y[rr][k] = 0.5f*acc[rr][k] + 24.f*ml[k];
  if (fg == 0) {
#pragma unroll
    for (int rr = 0; rr < 8; ++rr) ynorm[r0+rr] = y[rr][0];
  }
  __syncthreads();
#pragma unroll
  for (int rr = 0; rr < 8; ++rr) {
    float inv = 1.f / ynorm[r0+rr];
#pragma unroll
    for (int ff = 0; ff < 4; ++ff) {
      int f = f0 + ff;
      if (f >= 1 && f <= DD)
        attn[(size_t)(n0+r0+rr)*CC + h*DD + (f-1)] = y[rr][ff] * inv;
    }
  }
}

extern "C" void kernel_launch(void* const* d_in, const int* in_sizes, int n_in,
                              void* d_out, int out_size, void* d_ws, size_t ws_size,
                              hipStream_t stream) {
  const float* x      = (const float*)d_in[0];
  const float* qkv_w  = (const float*)d_in[1];
  const float* qkv_b  = (const float*)d_in[2];
  const float* proj_w = (const float*)d_in[3];
  const float* proj_b = (const float*)d_in[4];
  const float* temp   = (const float*)d_in[5];
  float* ws = (float*)d_ws;

  float* qkv = ws;                        // 4096*1152 = 4718592 floats (attn aliases this later)
  float* Qb  = ws + 4718592;              // 8*4096*64 = 2097152
  float* Kb  = Qb + 2097152;              // 2097152
  float* Vb  = Kb + 2097152;              // 2097152
  float* Mb  = Vb + 2097152;              // 2*8*50*4096 = 3276800
  float* attn = qkv;                      // qkv is dead after prep_kernel

  {
    dim3 g(4096/64, 1152/64);
    gemm_nt<<<g, 256, 0, stream>>>(x, qkv_w, qkv_b, qkv, 4096, 1152, 384);
  }
  prep_kernel<<<8192, 256, 0, stream>>>(qkv, temp, Qb, Kb, Vb);
  {
    dim3 g(DIS, HN, 2);
    kvmod_kernel<<<g, 256, 0, stream>>>(Kb, Vb, Mb);
  }
  {
    dim3 g(4096/128, HN);
    y_kernel<<<g, 256, 0, stream>>>(Qb, Mb, attn);
  }
  {
    dim3 g(4096/64, 384/64);
    gemm_nt<<<g, 256, 0, stream>>>(attn, proj_w, proj_b, (float*)d_out, 4096, 384, 384);
  }
}

// Round 3
// 272.291 us; speedup vs baseline: 2.5500x; 1.6635x over previous
//
#include <hip/hip_runtime.h>

#define HN 8
#define NN 4096
#define CC 384
#define DD 48
#define DP 64
#define NPAIR 1225   // (i<=j) over 49 channels
#define PPAD 1280
#define MPF 52       // f-padded row length of pair-major M

typedef unsigned short ushort;
typedef unsigned int uint;
typedef __attribute__((ext_vector_type(8))) short short8;
typedef __attribute__((ext_vector_type(4))) float f32x4;

__device__ __forceinline__ float4 ld4(const float* p){ return *reinterpret_cast<const float4*>(p); }
__device__ __forceinline__ void st4(float* p, const float4& v){ *reinterpret_cast<float4*>(p) = v; }

// RTN float->bf16 bits (inputs finite)
__device__ __forceinline__ uint bf16rtn(float x){
  uint u = __float_as_uint(x);
  return (u + 0x7FFFu + ((u >> 16) & 1u)) >> 16;
}

// ---------------- fp32 NT GEMM (unchanged) ----------------
__global__ __launch_bounds__(256) void gemm_nt(const float* __restrict__ A,
                                               const float* __restrict__ B,
                                               const float* __restrict__ bias,
                                               float* __restrict__ Cm,
                                               int M, int Nc, int K) {
  __shared__ float As[16*68];
  __shared__ float Bs[16*68];
  const int tid = threadIdx.x;
  const int m0 = blockIdx.x * 64;
  const int n0 = blockIdx.y * 64;
  const int lr = tid >> 2;
  const int lc = (tid & 3) << 2;
  const int r0 = (tid & 15) << 2;
  const int c0 = (tid >> 4) << 2;
  float acc[4][4] = {{0.f}};
  for (int k0 = 0; k0 < K; k0 += 16) {
    float4 a = ld4(A + (size_t)(m0 + lr) * K + k0 + lc);
    float4 b = ld4(B + (size_t)(n0 + lr) * K + k0 + lc);
    __syncthreads();
    As[(lc+0)*68+lr]=a.x; As[(lc+1)*68+lr]=a.y; As[(lc+2)*68+lr]=a.z; As[(lc+3)*68+lr]=a.w;
    Bs[(lc+0)*68+lr]=b.x; Bs[(lc+1)*68+lr]=b.y; Bs[(lc+2)*68+lr]=b.z; Bs[(lc+3)*68+lr]=b.w;
    __syncthreads();
#pragma unroll
    for (int kk = 0; kk < 16; ++kk) {
      float4 av = ld4(&As[kk*68 + r0]);
      float4 bv = ld4(&Bs[kk*68 + c0]);
      float aa[4] = {av.x, av.y, av.z, av.w};
      float bb[4] = {bv.x, bv.y, bv.z, bv.w};
#pragma unroll
      for (int u = 0; u < 4; ++u)
#pragma unroll
        for (int w = 0; w < 4; ++w)
          acc[u][w] += aa[u] * bb[w];
    }
  }
#pragma unroll
  for (int u = 0; u < 4; ++u) {
    float4 o;
    o.x = acc[u][0] + bias[n0+c0+0];
    o.y = acc[u][1] + bias[n0+c0+1];
    o.z = acc[u][2] + bias[n0+c0+2];
    o.w = acc[u][3] + bias[n0+c0+3];
    st4(Cm + (size_t)(m0 + r0 + u) * Nc + n0 + c0, o);
  }
}

// ---------------- prep: norms + layouts ----------------
// Qb   [h][n][64]  f32 (row-major, for y)
// KbT  [h][64][4096] f32 (transposed k~, channels 49..63 = 0)
// VhT/VlT [h][64][4096] bf16-bits (transposed split v1)
__global__ __launch_bounds__(256) void prep2(const float* __restrict__ qkv,
                                             const float* __restrict__ temperature,
                                             float* __restrict__ Qb,
                                             float* __restrict__ KbT,
                                             ushort* __restrict__ VhT,
                                             ushort* __restrict__ VlT) {
  __shared__ float Ks[64*65];
  __shared__ float Vs[64*65];
  const int nb = blockIdx.x;        // 0..63
  const int h  = blockIdx.y;
  const int lane = threadIdx.x & 63;
  const int w = threadIdx.x >> 6;
  const float temp = temperature[h];
  const float CINV = 0.05103103630798288f;   // 384^-0.5
  const float S4   = 2.6321480259049848f;    // 48^0.25
  for (int r = 0; r < 16; ++r) {
    const int nl = w*16 + r;
    const int n  = nb*64 + nl;
    const float* row = qkv + (size_t)n * (3*CC) + h * DD;
    float qv = (lane < DD) ? row[lane] : 0.f;
    float kv = (lane < DD) ? row[CC + lane] : 0.f;
    float vv = (lane >= 1 && lane <= DD) ? row[2*CC + lane - 1] : 0.f;
    float qs = qv * CINV;
    float q2 = qs * qs;
    float k2 = kv * kv;
#pragma unroll
    for (int off = 32; off > 0; off >>= 1) {
      q2 += __shfl_xor(q2, off);
      k2 += __shfl_xor(k2, off);
    }
    float qn = qs / fmaxf(sqrtf(q2), 1e-12f) * (S4 * temp);
    float kn = kv / fmaxf(sqrtf(k2), 1e-12f) * S4;
    float qo = (lane < DD) ? qn : ((lane == DD) ? 6.928203230275509f : 0.f);
    float ko = (lane < DD) ? kn : ((lane == DD) ? 1.f : 0.f);
    float vo = (lane == 0) ? (1.f/NN) : ((lane <= DD) ? vv * (1.f/NN) : 0.f);
    Qb[((size_t)h * NN + n) * DP + lane] = qo;
    Ks[nl*65 + lane] = ko;
    Vs[nl*65 + lane] = vo;
  }
  __syncthreads();
  // transposed writes
  const int ch = threadIdx.x >> 2;     // 0..63
  const int q4 = threadIdx.x & 3;      // 16-n group
  float kc[16], vc[16];
#pragma unroll
  for (int e = 0; e < 16; ++e) {
    int nl = q4*16 + e;
    kc[e] = Ks[nl*65 + ch];
    vc[e] = Vs[nl*65 + ch];
  }
  size_t tbase = ((size_t)h*64 + ch) * NN + nb*64 + q4*16;
#pragma unroll
  for (int e = 0; e < 16; e += 4)
    st4(KbT + tbase + e, make_float4(kc[e], kc[e+1], kc[e+2], kc[e+3]));
  // split v -> hi/lo bf16 packed
  uint hu[8], lu[8];
#pragma unroll
  for (int e = 0; e < 8; ++e) {
    float v0 = vc[2*e], v1 = vc[2*e+1];
    uint h0 = bf16rtn(v0), h1 = bf16rtn(v1);
    float d0 = v0 - __uint_as_float(h0 << 16);
    float d1 = v1 - __uint_as_float(h1 << 16);
    uint t0 = __float_as_uint(d0), t1 = __float_as_uint(d1);
    hu[e] = h0 | (h1 << 16);
    lu[e] = (t0 >> 16) | (t1 & 0xFFFF0000u);   // trunc lo
  }
  *reinterpret_cast<uint4*>(VhT + tbase)     = make_uint4(hu[0],hu[1],hu[2],hu[3]);
  *reinterpret_cast<uint4*>(VhT + tbase + 8) = make_uint4(hu[4],hu[5],hu[6],hu[7]);
  *reinterpret_cast<uint4*>(VlT + tbase)     = make_uint4(lu[0],lu[1],lu[2],lu[3]);
  *reinterpret_cast<uint4*>(VlT + tbase + 8) = make_uint4(lu[4],lu[5],lu[6],lu[7]);
}

// ---------------- kvmod via MFMA (split bf16) ----------------
// Mp[part][h][p][MPF] = sum_{n in part} KK[p][n] * V1[n][f]
#define KST 40   // ushort stride of KK/V LDS rows (80 B: 16B-aligned, ~2-way banks)
#define KNST 36  // f32 stride of staged k~ chunk
__global__ __launch_bounds__(256) void kvmod_mfma(const float* __restrict__ KbT,
                                                  const ushort* __restrict__ VhT,
                                                  const ushort* __restrict__ VlT,
                                                  float* __restrict__ Mp) {
  __shared__ ushort KKh[256*KST];
  __shared__ ushort KKl[256*KST];
  __shared__ float  KnS[64*KNST];
  __shared__ ushort VhS[64*KST];
  __shared__ ushort VlS[64*KST];
  const int tid  = threadIdx.x;
  const int p0   = blockIdx.x * 256;
  const int h    = blockIdx.y;
  const int part = blockIdx.z;
  const int nbase = part * 512;
  // pair decode (thread owns pair p0+tid)
  int ii = 63, jj = 63;
  {
    int pg = p0 + tid;
    if (pg < NPAIR) {
      int i = 0, rem = pg;
      while (rem >= 49 - i) { rem -= 49 - i; ++i; }
      ii = i; jj = i + rem;
    }
  }
  const float* krow_i = &KnS[ii*KNST];
  const float* krow_j = &KnS[jj*KNST];
  // staging coords
  const int sch = tid >> 2;       // 0..63 (channel / f row)
  const int sq  = tid & 3;        // 8-wide k quarter
  const size_t kgbase = ((size_t)h*64 + sch) * NN + nbase;
  // mfma coords
  const int lane = tid & 63, wv = tid >> 6;
  const int lr = lane & 15, lg = lane >> 4;
  f32x4 acc[4][4];
#pragma unroll
  for (int a = 0; a < 4; ++a)
#pragma unroll
    for (int b = 0; b < 4; ++b) acc[a][b] = (f32x4)0.f;

  for (int t = 0; t < 16; ++t) {
    const int k0 = t * 32;
    __syncthreads();   // previous mfma readers done
    // stage k~ chunk (f32) + V hi/lo chunk
    {
      float4 a0 = ld4(KbT + kgbase + k0 + sq*8);
      float4 a1 = ld4(KbT + kgbase + k0 + sq*8 + 4);
      st4(&KnS[sch*KNST + sq*8], a0);
      st4(&KnS[sch*KNST + sq*8 + 4], a1);
      *reinterpret_cast<uint4*>(&VhS[sch*KST + sq*8]) =
          *reinterpret_cast<const uint4*>(VhT + kgbase + k0 + sq*8);
      *reinterpret_cast<uint4*>(&VlS[sch*KST + sq*8]) =
          *reinterpret_cast<const uint4*>(VlT + kgbase + k0 + sq*8);
    }
    __syncthreads();   // KnS ready
    // form KK row (32 k) for pair p=tid, split hi/lo
    {
      uint hu[16], lu[16];
#pragma unroll
      for (int g = 0; g < 8; ++g) {
        float4 a = ld4(krow_i + g*4);
        float4 b = ld4(krow_j + g*4);
        float m0 = a.x*b.x, m1 = a.y*b.y, m2 = a.z*b.z, m3 = a.w*b.w;
        uint h0 = bf16rtn(m0), h1 = bf16rtn(m1), h2 = bf16rtn(m2), h3 = bf16rtn(m3);
        float d0 = m0 - __uint_as_float(h0 << 16);
        float d1 = m1 - __uint_as_float(h1 << 16);
        float d2 = m2 - __uint_as_float(h2 << 16);
        float d3 = m3 - __uint_as_float(h3 << 16);
        uint t0 = __float_as_uint(d0), t1 = __float_as_uint(d1);
        uint t2 = __float_as_uint(d2), t3 = __float_as_uint(d3);
        hu[2*g]   = h0 | (h1 << 16);
        hu[2*g+1] = h2 | (h3 << 16);
        lu[2*g]   = (t0 >> 16) | (t1 & 0xFFFF0000u);
        lu[2*g+1] = (t2 >> 16) | (t3 & 0xFFFF0000u);
      }
      uint4* dh = reinterpret_cast<uint4*>(&KKh[tid*KST]);
      uint4* dl = reinterpret_cast<uint4*>(&KKl[tid*KST]);
      dh[0] = make_uint4(hu[0],hu[1],hu[2],hu[3]);
      dh[1] = make_uint4(hu[4],hu[5],hu[6],hu[7]);
      dh[2] = make_uint4(hu[8],hu[9],hu[10],hu[11]);
      dh[3] = make_uint4(hu[12],hu[13],hu[14],hu[15]);
      dl[0] = make_uint4(lu[0],lu[1],lu[2],lu[3]);
      dl[1] = make_uint4(lu[4],lu[5],lu[6],lu[7]);
      dl[2] = make_uint4(lu[8],lu[9],lu[10],lu[11]);
      dl[3] = make_uint4(lu[12],lu[13],lu[14],lu[15]);
    }
    __syncthreads();   // KK ready
    // fragments + mfma
    short8 ah[4], al[4], bh[4], bl[4];
#pragma unroll
    for (int pf = 0; pf < 4; ++pf) {
      int prow = wv*64 + pf*16 + lr;
      ah[pf] = *reinterpret_cast<const short8*>(&KKh[prow*KST + lg*8]);
      al[pf] = *reinterpret_cast<const short8*>(&KKl[prow*KST + lg*8]);
    }
#pragma unroll
    for (int ff = 0; ff < 4; ++ff) {
      int frow = ff*16 + lr;
      bh[ff] = *reinterpret_cast<const short8*>(&VhS[frow*KST + lg*8]);
      bl[ff] = *reinterpret_cast<const short8*>(&VlS[frow*KST + lg*8]);
    }
#pragma unroll
    for (int pf = 0; pf < 4; ++pf)
#pragma unroll
      for (int ff = 0; ff < 4; ++ff) {
        acc[pf][ff] = __builtin_amdgcn_mfma_f32_16x16x32_bf16(ah[pf], bh[ff], acc[pf][ff], 0, 0, 0);
        acc[pf][ff] = __builtin_amdgcn_mfma_f32_16x16x32_bf16(ah[pf], bl[ff], acc[pf][ff], 0, 0, 0);
        acc[pf][ff] = __builtin_amdgcn_mfma_f32_16x16x32_bf16(al[pf], bh[ff], acc[pf][ff], 0, 0, 0);
      }
  }
  // epilogue: pair-major store
  float* out = Mp + ((size_t)(part*HN + h) * PPAD + p0 + wv*64) * MPF;
#pragma unroll
  for (int pf = 0; pf < 4; ++pf)
#pragma unroll
    for (int ff = 0; ff < 4; ++ff) {
      int f = ff*16 + lr;
      if (f < MPF) {
#pragma unroll
        for (int reg = 0; reg < 4; ++reg) {
          int prow = pf*16 + lg*4 + reg;
          out[prow*MPF + f] = acc[pf][ff][reg];
        }
      }
    }
}

// ---------------- reduce parts + mirror to slice layout ----------------
// Msl[h][i][j*64+f] = Msl[h][j][i*64+f] = sum_part Mp[part][h][p(i,j)][f]
__global__ __launch_bounds__(256) void reduce_mirror(const float* __restrict__ Mp,
                                                     float* __restrict__ Msl) {
  const int pb = blockIdx.x;      // 0..19
  const int h  = blockIdx.y;
  const int pl = threadIdx.x & 63;
  const int fq0 = threadIdx.x >> 6;   // 0..3
  const int p = pb*64 + pl;
  if (p >= NPAIR) return;
  int i = 0, rem = p;
  while (rem >= 49 - i) { rem -= 49 - i; ++i; }
  const int j = i + rem;
  for (int fq = fq0; fq < 13; fq += 4) {
    float4 s = make_float4(0.f, 0.f, 0.f, 0.f);
#pragma unroll
    for (int part = 0; part < 8; ++part) {
      float4 a = ld4(Mp + ((size_t)(part*HN + h) * PPAD + p) * MPF + fq*4);
      s.x += a.x; s.y += a.y; s.z += a.z; s.w += a.w;
    }
    st4(Msl + ((size_t)h*50 + i) * 4096 + j*64 + fq*4, s);
    st4(Msl + ((size_t)h*50 + j) * 4096 + i*64 + fq*4, s);
  }
}

// ---------------- y: triangle contraction (single M) ----------------
__global__ __launch_bounds__(256) void y_kernel(const float* __restrict__ Qb,
                                                const float* __restrict__ M,
                                                float* __restrict__ attn) {
  __shared__ float QsT[52*128];
  __shared__ float Ms[2*64*64];
  __shared__ float ynorm[128];
  const int tid = threadIdx.x;
  const int h = blockIdx.y;
  const int n0 = blockIdx.x * 128;
  const float* qb = Qb + ((size_t)h * NN + n0) * DP;
  for (int v = tid; v < 13*128; v += 256) {
    int r = v & 127;
    int cg = v >> 7;
    float4 q = ld4(qb + (size_t)r*DP + cg*4);
    QsT[(cg*4+0)*128 + r] = q.x;
    QsT[(cg*4+1)*128 + r] = q.y;
    QsT[(cg*4+2)*128 + r] = q.z;
    QsT[(cg*4+3)*128 + r] = q.w;
  }
  const int fg = tid & 15;
  const int rg = tid >> 4;
  const int f0 = fg << 2;
  const int r0 = rg << 3;
  float acc[8][4] = {{0.f}};
  const float* M0 = M + (size_t)h * 50 * 4096;
  for (int b = 0; b < 25; ++b) {
    const int i0 = 2*b;
    __syncthreads();
#pragma unroll
    for (int p = 0; p < 8; ++p) {
      int v = (tid + p*256) * 4;
      st4(&Ms[v], ld4(M0 + (size_t)i0*4096 + v));
    }
    __syncthreads();
    float qi1[8][2], qi2[8][2];
#pragma unroll
    for (int rr = 0; rr < 8; ++rr) {
      qi1[rr][0] = QsT[(i0+0)*128 + r0 + rr];
      qi1[rr][1] = QsT[(i0+1)*128 + r0 + rr];
      qi2[rr][0] = qi1[rr][0] + qi1[rr][0];
      qi2[rr][1] = qi1[rr][1] + qi1[rr][1];
    }
    {
      float4 m0 = ld4(&Ms[0*4096 + i0*64 + f0]);
#pragma unroll
      for (int rr = 0; rr < 8; ++rr) {
        float c = qi1[rr][0] * qi1[rr][0];
        acc[rr][0] += c*m0.x; acc[rr][1] += c*m0.y;
        acc[rr][2] += c*m0.z; acc[rr][3] += c*m0.w;
      }
    }
    {
      float4 m0 = ld4(&Ms[0*4096 + (i0+1)*64 + f0]);
      float4 m1 = ld4(&Ms[1*4096 + (i0+1)*64 + f0]);
#pragma unroll
      for (int rr = 0; rr < 8; ++rr) {
        float qj = qi1[rr][1];
        float c0 = qi2[rr][0] * qj;
        float c1 = qi1[rr][1] * qj;
        acc[rr][0] += c0*m0.x + c1*m1.x;
        acc[rr][1] += c0*m0.y + c1*m1.y;
        acc[rr][2] += c0*m0.z + c1*m1.z;
        acc[rr][3] += c0*m0.w + c1*m1.w;
      }
    }
#pragma unroll 2
    for (int j = i0+2; j < 50; ++j) {
      float4 qa = ld4(&QsT[j*128 + r0]);
      float4 qb2 = ld4(&QsT[j*128 + r0 + 4]);
      float qj[8] = {qa.x, qa.y, qa.z, qa.w, qb2.x, qb2.y, qb2.z, qb2.w};
      float4 m0 = ld4(&Ms[0*4096 + j*64 + f0]);
      float4 m1 = ld4(&Ms[1*4096 + j*64 + f0]);
#pragma unroll
      for (int rr = 0; rr < 8; ++rr) {
        float c0 = qi2[rr][0] * qj[rr];
        float c1 = qi2[rr][1] * qj[rr];
        acc[rr][0] += c0*m0.x + c1*m1.x;
        acc[rr][1] += c0*m0.y + c1*m1.y;
        acc[rr][2] += c0*m0.z + c1*m1.z;
        acc[rr][3] += c0*m0.w + c1*m1.w;
      }
    }
  }
  float4 e0 = ld4(M0 + (size_t)48*4096 + 48*64 + f0);
  float ml[4] = {e0.x, e0.y, e0.z, e0.w};
  float y[8][4];
#pragma unroll
  for (int rr = 0; rr < 8; ++rr)
#pragma unroll
    for (int k = 0; k < 4; ++k)
      y[rr][k] = 0.5f*acc[rr][k] + 24.f*ml[k];
  if (fg == 0) {
#pragma unroll
    for (int rr = 0; rr < 8; ++rr) ynorm[r0+rr] = y[rr][0];
  }
  __syncthreads();
#pragma unroll
  for (int rr = 0; rr < 8; ++rr) {
    float inv = 1.f / ynorm[r0+rr];
#pragma unroll
    for (int ff = 0; ff < 4; ++ff) {
      int f = f0 + ff;
      if (f >= 1 && f <= DD)
        attn[(size_t)(n0+r0+rr)*CC + h*DD + (f-1)] = y[rr][ff] * inv;
    }
  }
}

extern "C" void kernel_launch(void* const* d_in, const int* in_sizes, int n_in,
                              void* d_out, int out_size, void* d_ws, size_t ws_size,
                              hipStream_t stream) {
  const float* x      = (const float*)d_in[0];
  const float* qkv_w  = (const float*)d_in[1];
  const float* qkv_b  = (const float*)d_in[2];
  const float* proj_w = (const float*)d_in[3];
  const float* proj_b = (const float*)d_in[4];
  const float* temp   = (const float*)d_in[5];
  float* ws = (float*)d_ws;

  // Region A (4,718,592 f): qkv (gemm1->prep2), then Mp (kvmod->reduce), then attn (y->gemm2)
  float*  qkv = ws;
  float*  Mp  = ws;                      // 8*8*1280*52 = 4,259,840 f
  float*  attn = ws;                     // 4096*384 = 1,572,864 f
  // Region B: Qb
  float*  Qb  = ws + 4718592;            // 2,097,152 f
  // Region C: KbT | VhT | VlT ; Msl overlays KbT after kvmod
  float*  KbT = ws + 6815744;            // 2,097,152 f
  float*  Msl = KbT;                     // 8*50*4096 = 1,638,400 f (overlay, post-kvmod)
  ushort* VhT = (ushort*)(ws + 8912896); // 2,097,152 ushorts
  ushort* VlT = (ushort*)(ws + 9961472); // 2,097,152 ushorts

  {
    dim3 g(4096/64, 1152/64);
    gemm_nt<<<g, 256, 0, stream>>>(x, qkv_w, qkv_b, qkv, 4096, 1152, 384);
  }
  {
    dim3 g(64, HN);
    prep2<<<g, 256, 0, stream>>>(qkv, temp, Qb, KbT, VhT, VlT);
  }
  {
    dim3 g(PPAD/256, HN, 8);
    kvmod_mfma<<<g, 256, 0, stream>>>(KbT, VhT, VlT, Mp);
  }
  {
    dim3 g(PPAD/64, HN);
    reduce_mirror<<<g, 256, 0, stream>>>(Mp, Msl);
  }
  {
    dim3 g(4096/128, HN);
    y_kernel<<<g, 256, 0, stream>>>(Qb, Msl, attn);
  }
  {
    dim3 g(4096/64, 384/64);
    gemm_nt<<<g, 256, 0, stream>>>(attn, proj_w, proj_b, (float*)d_out, 4096, 384, 384);
  }
}

// Round 4
// 246.699 us; speedup vs baseline: 2.8145x; 1.1037x over previous
//
#include <hip/hip_runtime.h>

#define HN 8
#define NN 4096
#define CC 384
#define DD 48
#define DP 64
#define NPAIR 1225   // (i<=j) over 49 channels
#define PPAD 1280
#define MPF 52       // f-padded row length of pair-major M
#define QTS 128      // QT row stride (floats)

typedef unsigned short ushort;
typedef unsigned int uint;
typedef __attribute__((ext_vector_type(8))) short short8;
typedef __attribute__((ext_vector_type(4))) float f32x4;

__device__ __forceinline__ float4 ld4(const float* p){ return *reinterpret_cast<const float4*>(p); }
__device__ __forceinline__ void st4(float* p, const float4& v){ *reinterpret_cast<float4*>(p) = v; }

// RTN float->bf16 bits (inputs finite)
__device__ __forceinline__ uint bf16rtn(float x){
  uint u = __float_as_uint(x);
  return (u + 0x7FFFu + ((u >> 16) & 1u)) >> 16;
}

// ---------------- fp32 NT GEMM ----------------
__global__ __launch_bounds__(256) void gemm_nt(const float* __restrict__ A,
                                               const float* __restrict__ B,
                                               const float* __restrict__ bias,
                                               float* __restrict__ Cm,
                                               int M, int Nc, int K) {
  __shared__ float As[16*68];
  __shared__ float Bs[16*68];
  const int tid = threadIdx.x;
  const int m0 = blockIdx.x * 64;
  const int n0 = blockIdx.y * 64;
  const int lr = tid >> 2;
  const int lc = (tid & 3) << 2;
  const int r0 = (tid & 15) << 2;
  const int c0 = (tid >> 4) << 2;
  float acc[4][4] = {{0.f}};
  for (int k0 = 0; k0 < K; k0 += 16) {
    float4 a = ld4(A + (size_t)(m0 + lr) * K + k0 + lc);
    float4 b = ld4(B + (size_t)(n0 + lr) * K + k0 + lc);
    __syncthreads();
    As[(lc+0)*68+lr]=a.x; As[(lc+1)*68+lr]=a.y; As[(lc+2)*68+lr]=a.z; As[(lc+3)*68+lr]=a.w;
    Bs[(lc+0)*68+lr]=b.x; Bs[(lc+1)*68+lr]=b.y; Bs[(lc+2)*68+lr]=b.z; Bs[(lc+3)*68+lr]=b.w;
    __syncthreads();
#pragma unroll
    for (int kk = 0; kk < 16; ++kk) {
      float4 av = ld4(&As[kk*68 + r0]);
      float4 bv = ld4(&Bs[kk*68 + c0]);
      float aa[4] = {av.x, av.y, av.z, av.w};
      float bb[4] = {bv.x, bv.y, bv.z, bv.w};
#pragma unroll
      for (int u = 0; u < 4; ++u)
#pragma unroll
        for (int w = 0; w < 4; ++w)
          acc[u][w] += aa[u] * bb[w];
    }
  }
#pragma unroll
  for (int u = 0; u < 4; ++u) {
    float4 o;
    o.x = acc[u][0] + bias[n0+c0+0];
    o.y = acc[u][1] + bias[n0+c0+1];
    o.z = acc[u][2] + bias[n0+c0+2];
    o.w = acc[u][3] + bias[n0+c0+3];
    st4(Cm + (size_t)(m0 + r0 + u) * Nc + n0 + c0, o);
  }
}

// ---------------- prep: norms + layouts ----------------
__global__ __launch_bounds__(256) void prep2(const float* __restrict__ qkv,
                                             const float* __restrict__ temperature,
                                             float* __restrict__ Qb,
                                             float* __restrict__ KbT,
                                             ushort* __restrict__ VhT,
                                             ushort* __restrict__ VlT) {
  __shared__ float Ks[64*65];
  __shared__ float Vs[64*65];
  const int nb = blockIdx.x;        // 0..63
  const int h  = blockIdx.y;
  const int lane = threadIdx.x & 63;
  const int w = threadIdx.x >> 6;
  const float temp = temperature[h];
  const float CINV = 0.05103103630798288f;   // 384^-0.5
  const float S4   = 2.6321480259049848f;    // 48^0.25
  for (int r = 0; r < 16; ++r) {
    const int nl = w*16 + r;
    const int n  = nb*64 + nl;
    const float* row = qkv + (size_t)n * (3*CC) + h * DD;
    float qv = (lane < DD) ? row[lane] : 0.f;
    float kv = (lane < DD) ? row[CC + lane] : 0.f;
    float vv = (lane >= 1 && lane <= DD) ? row[2*CC + lane - 1] : 0.f;
    float qs = qv * CINV;
    float q2 = qs * qs;
    float k2 = kv * kv;
#pragma unroll
    for (int off = 32; off > 0; off >>= 1) {
      q2 += __shfl_xor(q2, off);
      k2 += __shfl_xor(k2, off);
    }
    float qn = qs / fmaxf(sqrtf(q2), 1e-12f) * (S4 * temp);
    float kn = kv / fmaxf(sqrtf(k2), 1e-12f) * S4;
    float qo = (lane < DD) ? qn : ((lane == DD) ? 6.928203230275509f : 0.f);
    float ko = (lane < DD) ? kn : ((lane == DD) ? 1.f : 0.f);
    float vo = (lane == 0) ? (1.f/NN) : ((lane <= DD) ? vv * (1.f/NN) : 0.f);
    Qb[((size_t)h * NN + n) * DP + lane] = qo;
    Ks[nl*65 + lane] = ko;
    Vs[nl*65 + lane] = vo;
  }
  __syncthreads();
  const int ch = threadIdx.x >> 2;
  const int q4 = threadIdx.x & 3;
  float kc[16], vc[16];
#pragma unroll
  for (int e = 0; e < 16; ++e) {
    int nl = q4*16 + e;
    kc[e] = Ks[nl*65 + ch];
    vc[e] = Vs[nl*65 + ch];
  }
  size_t tbase = ((size_t)h*64 + ch) * NN + nb*64 + q4*16;
#pragma unroll
  for (int e = 0; e < 16; e += 4)
    st4(KbT + tbase + e, make_float4(kc[e], kc[e+1], kc[e+2], kc[e+3]));
  uint hu[8], lu[8];
#pragma unroll
  for (int e = 0; e < 8; ++e) {
    float v0 = vc[2*e], v1 = vc[2*e+1];
    uint h0 = bf16rtn(v0), h1 = bf16rtn(v1);
    float d0 = v0 - __uint_as_float(h0 << 16);
    float d1 = v1 - __uint_as_float(h1 << 16);
    uint t0 = __float_as_uint(d0), t1 = __float_as_uint(d1);
    hu[e] = h0 | (h1 << 16);
    lu[e] = (t0 >> 16) | (t1 & 0xFFFF0000u);
  }
  *reinterpret_cast<uint4*>(VhT + tbase)     = make_uint4(hu[0],hu[1],hu[2],hu[3]);
  *reinterpret_cast<uint4*>(VhT + tbase + 8) = make_uint4(hu[4],hu[5],hu[6],hu[7]);
  *reinterpret_cast<uint4*>(VlT + tbase)     = make_uint4(lu[0],lu[1],lu[2],lu[3]);
  *reinterpret_cast<uint4*>(VlT + tbase + 8) = make_uint4(lu[4],lu[5],lu[6],lu[7]);
}

// ---------------- kvmod via MFMA (split bf16) ----------------
#define KST 40
#define KNST 36
__global__ __launch_bounds__(256) void kvmod_mfma(const float* __restrict__ KbT,
                                                  const ushort* __restrict__ VhT,
                                                  const ushort* __restrict__ VlT,
                                                  float* __restrict__ Mp) {
  __shared__ ushort KKh[256*KST];
  __shared__ ushort KKl[256*KST];
  __shared__ float  KnS[64*KNST];
  __shared__ ushort VhS[64*KST];
  __shared__ ushort VlS[64*KST];
  const int tid  = threadIdx.x;
  const int p0   = blockIdx.x * 256;
  const int h    = blockIdx.y;
  const int part = blockIdx.z;
  const int nbase = part * 512;
  int ii = 63, jj = 63;
  {
    int pg = p0 + tid;
    if (pg < NPAIR) {
      int i = 0, rem = pg;
      while (rem >= 49 - i) { rem -= 49 - i; ++i; }
      ii = i; jj = i + rem;
    }
  }
  const float* krow_i = &KnS[ii*KNST];
  const float* krow_j = &KnS[jj*KNST];
  const int sch = tid >> 2;
  const int sq  = tid & 3;
  const size_t kgbase = ((size_t)h*64 + sch) * NN + nbase;
  const int lane = tid & 63, wv = tid >> 6;
  const int lr = lane & 15, lg = lane >> 4;
  f32x4 acc[4][4];
#pragma unroll
  for (int a = 0; a < 4; ++a)
#pragma unroll
    for (int b = 0; b < 4; ++b) acc[a][b] = (f32x4)0.f;

  for (int t = 0; t < 16; ++t) {
    const int k0 = t * 32;
    __syncthreads();
    {
      float4 a0 = ld4(KbT + kgbase + k0 + sq*8);
      float4 a1 = ld4(KbT + kgbase + k0 + sq*8 + 4);
      st4(&KnS[sch*KNST + sq*8], a0);
      st4(&KnS[sch*KNST + sq*8 + 4], a1);
      *reinterpret_cast<uint4*>(&VhS[sch*KST + sq*8]) =
          *reinterpret_cast<const uint4*>(VhT + kgbase + k0 + sq*8);
      *reinterpret_cast<uint4*>(&VlS[sch*KST + sq*8]) =
          *reinterpret_cast<const uint4*>(VlT + kgbase + k0 + sq*8);
    }
    __syncthreads();
    {
      uint hu[16], lu[16];
#pragma unroll
      for (int g = 0; g < 8; ++g) {
        float4 a = ld4(krow_i + g*4);
        float4 b = ld4(krow_j + g*4);
        float m0 = a.x*b.x, m1 = a.y*b.y, m2 = a.z*b.z, m3 = a.w*b.w;
        uint h0 = bf16rtn(m0), h1 = bf16rtn(m1), h2 = bf16rtn(m2), h3 = bf16rtn(m3);
        float d0 = m0 - __uint_as_float(h0 << 16);
        float d1 = m1 - __uint_as_float(h1 << 16);
        float d2 = m2 - __uint_as_float(h2 << 16);
        float d3 = m3 - __uint_as_float(h3 << 16);
        uint t0 = __float_as_uint(d0), t1 = __float_as_uint(d1);
        uint t2 = __float_as_uint(d2), t3 = __float_as_uint(d3);
        hu[2*g]   = h0 | (h1 << 16);
        hu[2*g+1] = h2 | (h3 << 16);
        lu[2*g]   = (t0 >> 16) | (t1 & 0xFFFF0000u);
        lu[2*g+1] = (t2 >> 16) | (t3 & 0xFFFF0000u);
      }
      uint4* dh = reinterpret_cast<uint4*>(&KKh[tid*KST]);
      uint4* dl = reinterpret_cast<uint4*>(&KKl[tid*KST]);
      dh[0] = make_uint4(hu[0],hu[1],hu[2],hu[3]);
      dh[1] = make_uint4(hu[4],hu[5],hu[6],hu[7]);
      dh[2] = make_uint4(hu[8],hu[9],hu[10],hu[11]);
      dh[3] = make_uint4(hu[12],hu[13],hu[14],hu[15]);
      dl[0] = make_uint4(lu[0],lu[1],lu[2],lu[3]);
      dl[1] = make_uint4(lu[4],lu[5],lu[6],lu[7]);
      dl[2] = make_uint4(lu[8],lu[9],lu[10],lu[11]);
      dl[3] = make_uint4(lu[12],lu[13],lu[14],lu[15]);
    }
    __syncthreads();
    short8 ah[4], al[4], bh[4], bl[4];
#pragma unroll
    for (int pf = 0; pf < 4; ++pf) {
      int prow = wv*64 + pf*16 + lr;
      ah[pf] = *reinterpret_cast<const short8*>(&KKh[prow*KST + lg*8]);
      al[pf] = *reinterpret_cast<const short8*>(&KKl[prow*KST + lg*8]);
    }
#pragma unroll
    for (int ff = 0; ff < 4; ++ff) {
      int frow = ff*16 + lr;
      bh[ff] = *reinterpret_cast<const short8*>(&VhS[frow*KST + lg*8]);
      bl[ff] = *reinterpret_cast<const short8*>(&VlS[frow*KST + lg*8]);
    }
#pragma unroll
    for (int pf = 0; pf < 4; ++pf)
#pragma unroll
      for (int ff = 0; ff < 4; ++ff) {
        acc[pf][ff] = __builtin_amdgcn_mfma_f32_16x16x32_bf16(ah[pf], bh[ff], acc[pf][ff], 0, 0, 0);
        acc[pf][ff] = __builtin_amdgcn_mfma_f32_16x16x32_bf16(ah[pf], bl[ff], acc[pf][ff], 0, 0, 0);
        acc[pf][ff] = __builtin_amdgcn_mfma_f32_16x16x32_bf16(al[pf], bh[ff], acc[pf][ff], 0, 0, 0);
      }
  }
  float* out = Mp + ((size_t)(part*HN + h) * PPAD + p0 + wv*64) * MPF;
#pragma unroll
  for (int pf = 0; pf < 4; ++pf)
#pragma unroll
    for (int ff = 0; ff < 4; ++ff) {
      int f = ff*16 + lr;
      if (f < MPF) {
#pragma unroll
        for (int reg = 0; reg < 4; ++reg) {
          int prow = pf*16 + lg*4 + reg;
          out[prow*MPF + f] = acc[pf][ff][reg];
        }
      }
    }
}

// ---------------- reduce parts + mirror into f-major bf16 slices ----------------
// Mbh/Mbl[h][i][f][j] (i,j in 0..48 -> dims 49x64x64), Mnorm[h][64] = M[48][48][:]
__global__ __launch_bounds__(256) void reduce_mirror(const float* __restrict__ Mp,
                                                     ushort* __restrict__ Mbh,
                                                     ushort* __restrict__ Mbl,
                                                     float* __restrict__ Mnorm) {
  const int pb = blockIdx.x;      // 0..19
  const int h  = blockIdx.y;
  const int pl = threadIdx.x & 63;
  const int fq0 = threadIdx.x >> 6;   // 0..3
  const int p = pb*64 + pl;
  if (p >= NPAIR) return;
  int i = 0, rem = p;
  while (rem >= 49 - i) { rem -= 49 - i; ++i; }
  const int j = i + rem;
  for (int fq = fq0; fq < 13; fq += 4) {
    float4 s = make_float4(0.f, 0.f, 0.f, 0.f);
#pragma unroll
    for (int part = 0; part < 8; ++part) {
      float4 a = ld4(Mp + ((size_t)(part*HN + h) * PPAD + p) * MPF + fq*4);
      s.x += a.x; s.y += a.y; s.z += a.z; s.w += a.w;
    }
    float sv[4] = {s.x, s.y, s.z, s.w};
#pragma unroll
    for (int c = 0; c < 4; ++c) {
      int f = fq*4 + c;
      float v = sv[c];
      uint hb = bf16rtn(v);
      float d = v - __uint_as_float(hb << 16);
      ushort lb = (ushort)(__float_as_uint(d) >> 16);
      size_t a1 = (((size_t)h*49 + i)*64 + f)*64 + j;
      size_t a2 = (((size_t)h*49 + j)*64 + f)*64 + i;
      Mbh[a1] = (ushort)hb; Mbl[a1] = lb;
      Mbh[a2] = (ushort)hb; Mbl[a2] = lb;
    }
    if (p == NPAIR-1) st4(&Mnorm[h*64 + fq*4], s);   // pair (48,48)
  }
}

// ---------------- y via MFMA: y[n] = 0.5 * sum_i q_i * (q x M_i) + 24*ml ----------------
__global__ __launch_bounds__(256) void y_mfma(const float* __restrict__ Qb,
                                              const ushort* __restrict__ Mbh,
                                              const ushort* __restrict__ Mbl,
                                              const float* __restrict__ Mnorm,
                                              float* __restrict__ attn) {
  __shared__ float QT[52*QTS];        // q transposed: QT[i][row], 128 rows
  __shared__ ushort Mt[2][64*72];     // staged M_i hi/lo, [f][j] stride 72
  __shared__ float ynorm[128];
  const int tid = threadIdx.x;
  const int h = blockIdx.y;
  const int n0 = blockIdx.x * 128;
  const int lane = tid & 63;
  const int wv = tid >> 6;
  const int lr = lane & 15, lg = lane >> 4;

  // ---- stage QT (transpose 128x52 q-tile) ----
  {
    const int row = tid >> 1;
    const int half = tid & 1;
    const float* src = Qb + ((size_t)h*NN + n0 + row)*DP + half*32;
#pragma unroll
    for (int e = 0; e < 32; e += 4) {
      float4 v = ld4(src + e);
      int c = half*32 + e;
      if (c < 52) {
        QT[(c+0)*QTS + row] = v.x;
        if (c+1 < 52) QT[(c+1)*QTS + row] = v.y;
        if (c+2 < 52) QT[(c+2)*QTS + row] = v.z;
        if (c+3 < 52) QT[(c+3)*QTS + row] = v.w;
      }
    }
  }
  // ---- A-frags (constant over i-loop): rows = n0+wv*32+m*16+lr, k = kc*32+lg*8+e ----
  short8 ah[2][2], al[2][2];
#pragma unroll
  for (int m = 0; m < 2; ++m) {
    const float* qr = Qb + ((size_t)h*NN + n0 + wv*32 + m*16 + lr)*DP + lg*8;
#pragma unroll
    for (int kc = 0; kc < 2; ++kc) {
      float4 v0 = ld4(qr + kc*32);
      float4 v1 = ld4(qr + kc*32 + 4);
      float qv[8] = {v0.x,v0.y,v0.z,v0.w,v1.x,v1.y,v1.z,v1.w};
      union { uint u[4]; short8 s; } ch, cl;
#pragma unroll
      for (int e = 0; e < 4; ++e) {
        float x0 = qv[2*e], x1 = qv[2*e+1];
        uint h0 = bf16rtn(x0), h1 = bf16rtn(x1);
        float d0 = x0 - __uint_as_float(h0 << 16);
        float d1 = x1 - __uint_as_float(h1 << 16);
        ch.u[e] = h0 | (h1 << 16);
        cl.u[e] = (__float_as_uint(d0) >> 16) | (__float_as_uint(d1) & 0xFFFF0000u);
      }
      ah[m][kc] = ch.s;
      al[m][kc] = cl.s;
    }
  }
  // ---- M-slice staging coords ----
  const int ssp  = tid >> 7;          // 0=hi, 1=lo
  const int sidx = tid & 127;
  const int sf   = sidx >> 1;
  const int sjh  = sidx & 1;
  const ushort* Mbase = (ssp ? Mbl : Mbh) + ((size_t)h*49*64 + sf)*64 + sjh*32;
  uint4 pre[4];
#define LOAD_SLICE(I) {                                                   \
    const uint4* ms = reinterpret_cast<const uint4*>(Mbase + (size_t)(I)*4096); \
    pre[0] = ms[0]; pre[1] = ms[1]; pre[2] = ms[2]; pre[3] = ms[3]; }
#define WRITE_SLICE() {                                                   \
    uint4* dst = reinterpret_cast<uint4*>(&Mt[ssp][sf*72 + sjh*32]);      \
    dst[0] = pre[0]; dst[1] = pre[1]; dst[2] = pre[2]; dst[3] = pre[3]; }

  LOAD_SLICE(0);
  WRITE_SLICE();
  LOAD_SLICE(1);

  f32x4 ya[2][4];
#pragma unroll
  for (int m = 0; m < 2; ++m)
#pragma unroll
    for (int ff = 0; ff < 4; ++ff) ya[m][ff] = (f32x4)0.f;

  __syncthreads();
  for (int i = 0; i < 49; ++i) {
    // B-frags from Mt
    short8 bh[2][4], bl[2][4];
#pragma unroll
    for (int kc = 0; kc < 2; ++kc)
#pragma unroll
      for (int ff = 0; ff < 4; ++ff) {
        int f = ff*16 + lr;
        int j = kc*32 + lg*8;
        bh[kc][ff] = *reinterpret_cast<const short8*>(&Mt[0][f*72 + j]);
        bl[kc][ff] = *reinterpret_cast<const short8*>(&Mt[1][f*72 + j]);
      }
#pragma unroll
    for (int m = 0; m < 2; ++m) {
      float4 qi = ld4(&QT[i*QTS + wv*32 + m*16 + lg*4]);
#pragma unroll
      for (int ff = 0; ff < 4; ++ff) {
        f32x4 acc = (f32x4)0.f;
        acc = __builtin_amdgcn_mfma_f32_16x16x32_bf16(ah[m][0], bh[0][ff], acc, 0, 0, 0);
        acc = __builtin_amdgcn_mfma_f32_16x16x32_bf16(ah[m][0], bl[0][ff], acc, 0, 0, 0);
        acc = __builtin_amdgcn_mfma_f32_16x16x32_bf16(al[m][0], bh[0][ff], acc, 0, 0, 0);
        acc = __builtin_amdgcn_mfma_f32_16x16x32_bf16(ah[m][1], bh[1][ff], acc, 0, 0, 0);
        acc = __builtin_amdgcn_mfma_f32_16x16x32_bf16(ah[m][1], bl[1][ff], acc, 0, 0, 0);
        acc = __builtin_amdgcn_mfma_f32_16x16x32_bf16(al[m][1], bh[1][ff], acc, 0, 0, 0);
        ya[m][ff][0] += qi.x * acc[0];
        ya[m][ff][1] += qi.y * acc[1];
        ya[m][ff][2] += qi.z * acc[2];
        ya[m][ff][3] += qi.w * acc[3];
      }
    }
    __syncthreads();
    if (i < 48) {
      WRITE_SLICE();
      if (i < 47) LOAD_SLICE(i+2);
    }
    __syncthreads();
  }
  // ---- epilogue ----
  if (lr == 0) {
#pragma unroll
    for (int m = 0; m < 2; ++m)
#pragma unroll
      for (int r = 0; r < 4; ++r)
        ynorm[wv*32 + m*16 + lg*4 + r] = ya[m][0][r];
  }
  __syncthreads();
  const float ml0 = Mnorm[h*64];
  float mlf[4];
#pragma unroll
  for (int ff = 0; ff < 4; ++ff) mlf[ff] = Mnorm[h*64 + ff*16 + lr];
#pragma unroll
  for (int m = 0; m < 2; ++m) {
    float inv[4];
#pragma unroll
    for (int r = 0; r < 4; ++r)
      inv[r] = 1.f / (0.5f*ynorm[wv*32 + m*16 + lg*4 + r] + 24.f*ml0);
#pragma unroll
    for (int ff = 0; ff < 4; ++ff) {
      int f = ff*16 + lr;
      if (f >= 1 && f <= 48) {
#pragma unroll
        for (int r = 0; r < 4; ++r) {
          int row = n0 + wv*32 + m*16 + lg*4 + r;
          float yv = 0.5f*ya[m][ff][r] + 24.f*mlf[ff];
          attn[(size_t)row*CC + h*DD + (f-1)] = yv * inv[r];
        }
      }
    }
  }
}

extern "C" void kernel_launch(void* const* d_in, const int* in_sizes, int n_in,
                              void* d_out, int out_size, void* d_ws, size_t ws_size,
                              hipStream_t stream) {
  const float* x      = (const float*)d_in[0];
  const float* qkv_w  = (const float*)d_in[1];
  const float* qkv_b  = (const float*)d_in[2];
  const float* proj_w = (const float*)d_in[3];
  const float* proj_b = (const float*)d_in[4];
  const float* temp   = (const float*)d_in[5];
  float* ws = (float*)d_ws;

  // Region A: qkv (gemm1->prep2) -> Mp (kvmod->reduce) -> attn (y->gemm2)
  float*  qkv  = ws;
  float*  Mp   = ws;                      // 8*8*1280*52 = 4,259,840 f
  float*  attn = ws;                      // 1,572,864 f
  // Region B
  float*  Qb   = ws + 4718592;            // 2,097,152 f
  // Region C: KbT (live until kvmod) -> Mbh|Mbl|Mnorm (reduce -> y)
  float*  KbT  = ws + 6815744;            // 2,097,152 f
  ushort* Mbh  = (ushort*)(ws + 6815744); // 8*49*64*64 = 1,605,632 us (802,816 f)
  ushort* Mbl  = Mbh + 1605632;           //            (802,816 f)
  float*  Mnorm= ws + 6815744 + 1605632;  // 512 f
  // Region D
  ushort* VhT  = (ushort*)(ws + 8912896); // 2,097,152 us
  ushort* VlT  = (ushort*)(ws + 9961472); // 2,097,152 us

  {
    dim3 g(4096/64, 1152/64);
    gemm_nt<<<g, 256, 0, stream>>>(x, qkv_w, qkv_b, qkv, 4096, 1152, 384);
  }
  {
    dim3 g(64, HN);
    prep2<<<g, 256, 0, stream>>>(qkv, temp, Qb, KbT, VhT, VlT);
  }
  {
    dim3 g(PPAD/256, HN, 8);
    kvmod_mfma<<<g, 256, 0, stream>>>(KbT, VhT, VlT, Mp);
  }
  // zero Mbh|Mbl|Mnorm (j>=49 / f>=52 padding must be 0); KbT is dead now
  hipMemsetAsync((void*)Mbh, 0, 2*(size_t)1605632*2 + 2048, stream);
  {
    dim3 g(PPAD/64, HN);
    reduce_mirror<<<g, 256, 0, stream>>>(Mp, Mbh, Mbl, Mnorm);
  }
  {
    dim3 g(4096/128, HN);
    y_mfma<<<g, 256, 0, stream>>>(Qb, Mbh, Mbl, Mnorm, attn);
  }
  {
    dim3 g(4096/64, 384/64);
    gemm_nt<<<g, 256, 0, stream>>>(attn, proj_w, proj_b, (float*)d_out, 4096, 384, 384);
  }
}